// Round 11
// baseline (337.677 us; speedup 1.0000x reference)
//
#include <hip/hip_runtime.h>

// Dims (fixed): S=4096, N=32, E=512, H=8, DK=64. Query pos l = 2048 (L==1).
// qb = q.bk cancels in softmax (constant over s) -> dropped everywhere.
#define SS 4096
#define NB 32
#define EE 512
#define HH 8
#define DKK 64
#define LQ 2048
#define NCHUNK 16          // s-chunks per n in fused phase (256 s each)
#define NBLK 512           // grid size; co-resident at 2 blocks/CU x 256 CU

// DPP cross-lane add: dst += perm(src) on the VALU pipe (no DS).
// 0xB1 quad_perm(1,0,3,2)=xor1; 0x4E quad_perm(2,3,0,1)=xor2;
// 0x141 ROW_HALF_MIRROR=xor7 (within 8); 0x128 ROW_ROR:8=xor8 (within 16).
#define DPPADD(dst, src, ctrl)                                              \
  dst += __int_as_float(__builtin_amdgcn_update_dpp(                        \
      0, __float_as_int(src), ctrl, 0xF, 0xF, true))

// Resident-grid barrier: all NBLK blocks are co-resident by occupancy
// arithmetic (launch_bounds(256,2), LDS 64.2KB); distinct counter per phase,
// zeroed by hipMemsetAsync before launch. Producer: release fence + add.
// Consumer: spin (s_sleep) then acquire fence.
__device__ __forceinline__ void gridbar(unsigned* bar, int idx, int tid) {
  __syncthreads();
  if (tid == 0) {
    __threadfence();
    atomicAdd(&bar[idx], 1u);
    while (__hip_atomic_load(&bar[idx], __ATOMIC_RELAXED,
                             __HIP_MEMORY_SCOPE_AGENT) < (unsigned)NBLK)
      __builtin_amdgcn_s_sleep(8);
  }
  __syncthreads();
  __threadfence();
}

// One persistent kernel, 5 phases, 4 grid barriers. Grid 512x256, 2 blk/CU.
__global__ __launch_bounds__(256, 2) void k_mega(
    const float* __restrict__ src, const float* __restrict__ Wq,
    const float* __restrict__ bq, const float* __restrict__ Wk,
    const float* __restrict__ Wv, const float* __restrict__ bv,
    const float* __restrict__ Wo, const float* __restrict__ bo,
    const float* __restrict__ Wl, const float* __restrict__ bl,
    float* __restrict__ qk, float* __restrict__ lw, float* __restrict__ part,
    float* __restrict__ vout, float* __restrict__ y1, float* __restrict__ out,
    unsigned* __restrict__ bar) {
  __shared__ float4 cb4[4][HH * EE / 4];  // 64 KB (aliased by phases 0/2)
  __shared__ float lbuf[4 * HH];

  int bx = blockIdx.x;
  int tid = threadIdx.x, wave = tid >> 6, lane = tid & 63;
  const int SLOT[8] = {0, 1, 2, 3, 7, 6, 5, 4};

  // ---------------- phase 0: qproj (blocks 0..255 = (n,h)) -----------------
  if (bx < 256) {
    float* qd = (float*)&cb4[0][0];
    int n = bx >> 3, h = bx & 7;
    int d = tid >> 2, part4 = tid & 3;
    const float4* xs = (const float4*)(src + ((size_t)LQ * NB + n) * EE);
    const float4* wr = (const float4*)(Wq + (size_t)(h * DKK + d) * EE);
    float acc = 0.f;
#pragma unroll 8
    for (int i = 0; i < 32; ++i) {
      float4 a = xs[part4 * 32 + i], b = wr[part4 * 32 + i];
      acc = fmaf(a.x, b.x, fmaf(a.y, b.y, fmaf(a.z, b.z, fmaf(a.w, b.w, acc))));
    }
    DPPADD(acc, acc, 0xB1);   // xor1
    DPPADD(acc, acc, 0x4E);   // xor2
    if (part4 == 0) qd[d] = acc + bq[h * DKK + d];
    __syncthreads();
    float a0 = 0.f, a1 = 0.f;
#pragma unroll 8
    for (int d2 = 0; d2 < DKK; ++d2) {
      float qv = qd[d2];
      const float* row = Wk + (size_t)(h * DKK + d2) * EE;
      a0 = fmaf(qv, row[tid], a0);
      a1 = fmaf(qv, row[tid + 256], a1);
    }
    size_t base = (size_t)(n * HH + h) * EE;
    qk[base + tid] = a0;
    qk[base + tid + 256] = a1;
  }
  gridbar(bar, 0, tid);

  // ---------------- phase 1: fused scores+softmax+ctx (all 512) ------------
  {
    int n = bx >> 4, c = bx & 15;
    const float4* qk4 = (const float4*)qk;
    float4 qf[16];
#pragma unroll
    for (int j = 0; j < HH; ++j) {
      int hj = (lane & 7) ^ SLOT[j];
      int qbase = (n * HH + hj) * (EE / 4);
      qf[2 * j] = qk4[qbase + lane];
      qf[2 * j + 1] = qk4[qbase + 64 + lane];
    }
    float4 acc[16];   // head-major: acc[2h], acc[2h+1]
#pragma unroll
    for (int i = 0; i < 16; ++i) acc[i] = make_float4(0.f, 0.f, 0.f, 0.f);
    float lp = 0.f;

    const size_t rowstep = (size_t)NB * (EE / 4);
    const float4* sp = (const float4*)src +
                       ((size_t)((c << 8) + wave * 2) * NB + n) * (EE / 4);
    float4 cA0 = sp[lane], cA1 = sp[64 + lane];
    float4 cB0 = sp[rowstep + lane], cB1 = sp[rowstep + 64 + lane];
    sp += 8 * rowstep;
    float4 nA0 = sp[lane], nA1 = sp[64 + lane];
    float4 nB0 = sp[rowstep + lane], nB1 = sp[rowstep + 64 + lane];

#pragma unroll 2
    for (int it = 0; it < 32; ++it) {
      float4 aA = cA0, dA = cA1, aB = cB0, dB = cB1;
      cA0 = nA0; cA1 = nA1; cB0 = nB0; cB1 = nB1;
      if (it < 30) {
        sp += 8 * rowstep;
        nA0 = sp[lane]; nA1 = sp[64 + lane];
        nB0 = sp[rowstep + lane]; nB1 = sp[rowstep + 64 + lane];
      }
      float pA[8], pB[8];
#pragma unroll
      for (int j = 0; j < HH; ++j) {
        float4 u = qf[2 * j], v = qf[2 * j + 1];
        pA[j] = fmaf(aA.x, u.x, fmaf(aA.y, u.y, fmaf(aA.z, u.z, fmaf(aA.w, u.w,
                fmaf(dA.x, v.x, fmaf(dA.y, v.y, fmaf(dA.z, v.z, dA.w * v.w)))))));
        pB[j] = fmaf(aB.x, u.x, fmaf(aB.y, u.y, fmaf(aB.z, u.z, fmaf(aB.w, u.w,
                fmaf(dB.x, v.x, fmaf(dB.y, v.y, fmaf(dB.z, v.z, dB.w * v.w)))))));
      }
      DPPADD(pA[0], pA[1], 0xB1);  DPPADD(pB[0], pB[1], 0xB1);
      DPPADD(pA[2], pA[3], 0xB1);  DPPADD(pB[2], pB[3], 0xB1);
      DPPADD(pA[4], pA[5], 0xB1);  DPPADD(pB[4], pB[5], 0xB1);
      DPPADD(pA[6], pA[7], 0xB1);  DPPADD(pB[6], pB[7], 0xB1);
      DPPADD(pA[0], pA[2], 0x4E);  DPPADD(pB[0], pB[2], 0x4E);
      DPPADD(pA[4], pA[6], 0x4E);  DPPADD(pB[4], pB[6], 0x4E);
      DPPADD(pA[0], pA[4], 0x141); DPPADD(pB[0], pB[4], 0x141);
      DPPADD(pA[0], pA[0], 0x128); DPPADD(pB[0], pB[0], 0x128);
      pA[0] += __shfl_xor(pA[0], 16, 64);
      pB[0] += __shfl_xor(pB[0], 16, 64);
      pA[0] += __shfl_xor(pA[0], 32, 64);
      pB[0] += __shfl_xor(pB[0], 32, 64);
      float eA = __expf(pA[0] * 0.125f);
      float eB = __expf(pB[0] * 0.125f);
      lp += eA + eB;
      float wA[8], wB[8];
#pragma unroll
      for (int h = 0; h < HH; ++h) {
        wA[h] = __uint_as_float(__builtin_amdgcn_readlane(__float_as_uint(eA), h));
        wB[h] = __uint_as_float(__builtin_amdgcn_readlane(__float_as_uint(eB), h));
      }
#pragma unroll
      for (int h = 0; h < HH; ++h) {
        float w1 = wA[h], w2 = wB[h];
        acc[2 * h].x = fmaf(w1, aA.x, acc[2 * h].x);
        acc[2 * h].y = fmaf(w1, aA.y, acc[2 * h].y);
        acc[2 * h].z = fmaf(w1, aA.z, acc[2 * h].z);
        acc[2 * h].w = fmaf(w1, aA.w, acc[2 * h].w);
        acc[2 * h + 1].x = fmaf(w1, dA.x, acc[2 * h + 1].x);
        acc[2 * h + 1].y = fmaf(w1, dA.y, acc[2 * h + 1].y);
        acc[2 * h + 1].z = fmaf(w1, dA.z, acc[2 * h + 1].z);
        acc[2 * h + 1].w = fmaf(w1, dA.w, acc[2 * h + 1].w);
        acc[2 * h].x = fmaf(w2, aB.x, acc[2 * h].x);
        acc[2 * h].y = fmaf(w2, aB.y, acc[2 * h].y);
        acc[2 * h].z = fmaf(w2, aB.z, acc[2 * h].z);
        acc[2 * h].w = fmaf(w2, aB.w, acc[2 * h].w);
        acc[2 * h + 1].x = fmaf(w2, dB.x, acc[2 * h + 1].x);
        acc[2 * h + 1].y = fmaf(w2, dB.y, acc[2 * h + 1].y);
        acc[2 * h + 1].z = fmaf(w2, dB.z, acc[2 * h + 1].z);
        acc[2 * h + 1].w = fmaf(w2, dB.w, acc[2 * h + 1].w);
      }
    }

    // epilogue: wave-private slices, one barrier, parallel combine
    __syncthreads();   // phase-0 LDS (qd alias) fully consumed before reuse
#pragma unroll
    for (int h = 0; h < HH; ++h) {
      cb4[wave][h * 128 + lane] = acc[2 * h];
      cb4[wave][h * 128 + 64 + lane] = acc[2 * h + 1];
    }
    if (lane < 8) lbuf[wave * 8 + lane] = lp;
    __syncthreads();
    float4* pb4 = (float4*)(part + (size_t)bx * (HH * EE));
#pragma unroll
    for (int j = 0; j < 4; ++j) {
      int idx = tid + j * 256;
      float4 s0 = cb4[0][idx], s1 = cb4[1][idx], s2 = cb4[2][idx], s3 = cb4[3][idx];
      float4 o;
      o.x = s0.x + s1.x + s2.x + s3.x;
      o.y = s0.y + s1.y + s2.y + s3.y;
      o.z = s0.z + s1.z + s2.z + s3.z;
      o.w = s0.w + s1.w + s2.w + s3.w;
      pb4[idx] = o;
    }
    if (tid < 8)
      lw[bx * 8 + tid] = lbuf[tid] + lbuf[8 + tid] + lbuf[16 + tid] + lbuf[24 + tid];
  }
  gridbar(bar, 1, tid);

  // ---------------- phase 2: combine + normalize + Wv (blocks 0..255) ------
  if (bx < 256) {
    float* ctxs = (float*)&cb4[0][0];
    int n = bx >> 3, h = bx & 7;
    if (tid < 16) {
      float l = lw[(n * NCHUNK + tid) * 8 + h];
      DPPADD(l, l, 0xB1);    // xor1
      DPPADD(l, l, 0x4E);    // xor2
      DPPADD(l, l, 0x141);   // xor7
      DPPADD(l, l, 0x128);   // xor8 -> full 16-sum
      if (tid == 0) lbuf[0] = 1.f / l;
    }
    float s0 = 0.f, s1 = 0.f;
#pragma unroll
    for (int c2 = 0; c2 < NCHUNK; ++c2) {
      const float* pb = part + (size_t)(n * NCHUNK + c2) * 4096 + h * EE;
      s0 += pb[tid];
      s1 += pb[tid + 256];
    }
    ctxs[tid] = s0;
    ctxs[tid + 256] = s1;
    __syncthreads();
    const float4* cx = (const float4*)ctxs;
    float4 c0 = cx[lane], c1 = cx[64 + lane];
    float li = lbuf[0];
    const float4* Wv4 = (const float4*)Wv;
#pragma unroll 4
    for (int k = 0; k < 16; ++k) {
      int r = h * 64 + wave * 16 + k;
      float4 w0 = Wv4[(size_t)r * 128 + lane], w1 = Wv4[(size_t)r * 128 + 64 + lane];
      float d = fmaf(c0.x, w0.x, fmaf(c0.y, w0.y, fmaf(c0.z, w0.z, fmaf(c0.w, w0.w,
                fmaf(c1.x, w1.x, fmaf(c1.y, w1.y, fmaf(c1.z, w1.z, c1.w * w1.w)))))));
      DPPADD(d, d, 0xB1);
      DPPADD(d, d, 0x4E);
      DPPADD(d, d, 0x141);
      DPPADD(d, d, 0x128);
      d += __shfl_xor(d, 16, 64);
      d += __shfl_xor(d, 32, 64);
      if (lane == 0) vout[(size_t)n * EE + r] = d * li + bv[r];
    }
  }
  gridbar(bar, 2, tid);

  // ---------------- phase 3: gemv y1 = vout.Wo^T + bo (wave = virt block) --
  {
    int r = bx, g = wave;   // virt block vb = bx*4+wave -> r, g
    const float4* W4 = (const float4*)Wo;
    const float4* x4 = (const float4*)vout;
    float4 w0 = W4[r * 128 + lane];
    float4 w1 = W4[r * 128 + 64 + lane];
    float acc[8];
#pragma unroll
    for (int j = 0; j < 8; ++j) {
      int n = g * 8 + ((lane & 7) ^ SLOT[j]);
      float4 a = x4[n * 128 + lane], d = x4[n * 128 + 64 + lane];
      acc[j] = fmaf(a.x, w0.x, fmaf(a.y, w0.y, fmaf(a.z, w0.z, fmaf(a.w, w0.w,
               fmaf(d.x, w1.x, fmaf(d.y, w1.y, fmaf(d.z, w1.z, d.w * w1.w)))))));
    }
    DPPADD(acc[0], acc[1], 0xB1);
    DPPADD(acc[2], acc[3], 0xB1);
    DPPADD(acc[4], acc[5], 0xB1);
    DPPADD(acc[6], acc[7], 0xB1);
    DPPADD(acc[0], acc[2], 0x4E);
    DPPADD(acc[4], acc[6], 0x4E);
    DPPADD(acc[0], acc[4], 0x141);
    DPPADD(acc[0], acc[0], 0x128);
    acc[0] += __shfl_xor(acc[0], 16, 64);
    acc[0] += __shfl_xor(acc[0], 32, 64);
    if (lane < 8) y1[(size_t)(g * 8 + lane) * EE + r] = acc[0] + bo[r];
  }
  gridbar(bar, 3, tid);

  // ---------------- phase 4: gemv out = y1.Wl^T + bl -----------------------
  {
    int r = bx, g = wave;
    const float4* W4 = (const float4*)Wl;
    const float4* x4 = (const float4*)y1;
    float4 w0 = W4[r * 128 + lane];
    float4 w1 = W4[r * 128 + 64 + lane];
    float acc[8];
#pragma unroll
    for (int j = 0; j < 8; ++j) {
      int n = g * 8 + ((lane & 7) ^ SLOT[j]);
      float4 a = x4[n * 128 + lane], d = x4[n * 128 + 64 + lane];
      acc[j] = fmaf(a.x, w0.x, fmaf(a.y, w0.y, fmaf(a.z, w0.z, fmaf(a.w, w0.w,
               fmaf(d.x, w1.x, fmaf(d.y, w1.y, fmaf(d.z, w1.z, d.w * w1.w)))))));
    }
    DPPADD(acc[0], acc[1], 0xB1);
    DPPADD(acc[2], acc[3], 0xB1);
    DPPADD(acc[4], acc[5], 0xB1);
    DPPADD(acc[6], acc[7], 0xB1);
    DPPADD(acc[0], acc[2], 0x4E);
    DPPADD(acc[4], acc[6], 0x4E);
    DPPADD(acc[0], acc[4], 0x141);
    DPPADD(acc[0], acc[0], 0x128);
    acc[0] += __shfl_xor(acc[0], 16, 64);
    acc[0] += __shfl_xor(acc[0], 32, 64);
    if (lane < 8) out[(size_t)(g * 8 + lane) * EE + r] = acc[0] + bl[r];
  }
}

extern "C" void kernel_launch(void* const* d_in, const int* in_sizes, int n_in,
                              void* d_out, int out_size, void* d_ws, size_t ws_size,
                              hipStream_t stream) {
  const float* src = (const float*)d_in[0];
  const float* Wq  = (const float*)d_in[1];
  const float* bq  = (const float*)d_in[2];
  const float* Wk  = (const float*)d_in[3];
  const float* Wv  = (const float*)d_in[5];
  const float* bv  = (const float*)d_in[6];
  const float* Wo  = (const float*)d_in[7];
  const float* bo  = (const float*)d_in[8];
  const float* Wl  = (const float*)d_in[9];
  const float* bl  = (const float*)d_in[10];
  float* out = (float*)d_out;

  float* ws = (float*)d_ws;
  float* qk   = ws;                               // 131072
  float* lw   = qk + 131072;                      // 512*8 = 4096
  float* vout = lw + 4096;                        // 16384
  float* y1   = vout + 16384;                     // 16384
  unsigned* bar = (unsigned*)(y1 + 16384);        // 16 counters (64 B)
  float* part = y1 + 16384 + 64;                  // 512*4096 floats (8MB)

  hipMemsetAsync(bar, 0, 16 * sizeof(unsigned), stream);
  k_mega<<<NBLK, 256, 0, stream>>>(src, Wq, bq, Wk, Wv, bv, Wo, bo, Wl, bl,
                                   qk, lw, part, vout, y1, out, bar);
}

// Round 12
// 79.984 us; speedup vs baseline: 4.2218x; 4.2218x over previous
//
#include <hip/hip_runtime.h>

// Dims (fixed): S=4096, N=32, E=512, H=8, DK=64. Query pos l = 2048 (L==1).
// qb = q.bk cancels in softmax (constant over s) -> dropped everywhere.
#define SS 4096
#define NB 32
#define EE 512
#define HH 8
#define DKK 64
#define LQ 2048
#define NCHUNK 16          // s-chunks per n in fused kernel (256 s each)

// DPP cross-lane add: dst += perm(src) on the VALU pipe (no DS).
// 0xB1 quad_perm(1,0,3,2)=xor1; 0x4E quad_perm(2,3,0,1)=xor2;
// 0x141 ROW_HALF_MIRROR=xor7 (within 8); 0x128 ROW_ROR:8=xor8 (within 16).
#define DPPADD(dst, src, ctrl)                                              \
  dst += __int_as_float(__builtin_amdgcn_update_dpp(                        \
      0, __float_as_int(src), ctrl, 0xF, 0xF, true))

// Nontemporal float4 load: src is a read-once 268MB stream -> nt bit keeps
// it from polluting L1/L2 (qk/part stay hot). ext_vector type keeps the
// clang builtin happy (HIP float4 is a struct).
typedef float f32x4v __attribute__((ext_vector_type(4)));
__device__ __forceinline__ float4 ntload(const float4* p) {
  f32x4v t = __builtin_nontemporal_load((const f32x4v*)p);
  return make_float4(t.x, t.y, t.z, t.w);
}

// ---- K1: q[n,h,:] then qk[n,h,e] = sum_d q_d * Wk[h*64+d, e] ---------------
__global__ __launch_bounds__(256) void k_qproj(const float* __restrict__ src,
                                               const float* __restrict__ Wq,
                                               const float* __restrict__ bq,
                                               const float* __restrict__ Wk,
                                               float* __restrict__ qk) {
  __shared__ float qd[DKK];
  int n = blockIdx.x >> 3, h = blockIdx.x & 7;
  int tid = threadIdx.x;
  int d = tid >> 2, part = tid & 3;
  const float4* xs = (const float4*)(src + ((size_t)LQ * NB + n) * EE);
  const float4* wr = (const float4*)(Wq + (size_t)(h * DKK + d) * EE);
  float acc = 0.f;
#pragma unroll 8
  for (int i = 0; i < 32; ++i) {
    float4 a = xs[part * 32 + i], b = wr[part * 32 + i];
    acc = fmaf(a.x, b.x, fmaf(a.y, b.y, fmaf(a.z, b.z, fmaf(a.w, b.w, acc))));
  }
  DPPADD(acc, acc, 0xB1);   // xor1
  DPPADD(acc, acc, 0x4E);   // xor2
  if (part == 0) qd[d] = acc + bq[h * DKK + d];
  __syncthreads();
  float a0 = 0.f, a1 = 0.f;
#pragma unroll 8
  for (int d2 = 0; d2 < DKK; ++d2) {
    float qv = qd[d2];
    const float* row = Wk + (size_t)(h * DKK + d2) * EE;
    a0 = fmaf(qv, row[tid], a0);
    a1 = fmaf(qv, row[tid + 256], a1);
  }
  size_t base = (size_t)(n * HH + h) * EE;
  qk[base + tid] = a0;
  qk[base + tid + 256] = a1;
}

// ---- K2 (fused): one pass over src; 2 rows/wave-iter (ILP).
// Slot offsets s = {0,1,2,3,7,6,5,4}: slot j of lane L holds head (L&7)^s_j.
// Fold uses DPP masks {1,2,7,8} + shfl {16,32}. Lane L ends with the full dot
// for head L&7; weights wave-uniform -> readlane to SGPR. src via nt loads.
__global__ __launch_bounds__(256, 2) void k_fused(const float* __restrict__ src,
                                                  const float* __restrict__ qk,
                                                  float* __restrict__ part,
                                                  float* __restrict__ lw) {
  __shared__ float cbuf[HH * EE];   // 16 KB
  __shared__ float lbuf[4 * HH];
  int b = blockIdx.x;
  int n = b >> 4, c = b & 15;
  int tid = threadIdx.x, wave = tid >> 6, lane = tid & 63;

  const int SLOT[8] = {0, 1, 2, 3, 7, 6, 5, 4};
  const float4* qk4 = (const float4*)qk;
  float4 qf[16];
#pragma unroll
  for (int j = 0; j < HH; ++j) {
    int hj = (lane & 7) ^ SLOT[j];
    int qbase = (n * HH + hj) * (EE / 4);
    qf[2 * j] = qk4[qbase + lane];
    qf[2 * j + 1] = qk4[qbase + 64 + lane];
  }

  float4 acc[16];   // head-major: acc[2h], acc[2h+1]
#pragma unroll
  for (int i = 0; i < 16; ++i) acc[i] = make_float4(0.f, 0.f, 0.f, 0.f);
  float lp = 0.f;

  const size_t rowstep = (size_t)NB * (EE / 4);   // float4 step for s+1
  const float4* sp = (const float4*)src +
                     ((size_t)((c << 8) + wave * 2) * NB + n) * (EE / 4);
  float4 nA0 = ntload(sp + lane), nA1 = ntload(sp + 64 + lane);
  float4 nB0 = ntload(sp + rowstep + lane), nB1 = ntload(sp + rowstep + 64 + lane);

  for (int it = 0; it < 32; ++it) {
    float4 aA = nA0, dA = nA1, aB = nB0, dB = nB1;
    if (it < 31) {
      sp += 8 * rowstep;
      nA0 = ntload(sp + lane); nA1 = ntload(sp + 64 + lane);
      nB0 = ntload(sp + rowstep + lane); nB1 = ntload(sp + rowstep + 64 + lane);
    }
    float pA[8], pB[8];
#pragma unroll
    for (int j = 0; j < HH; ++j) {
      float4 u = qf[2 * j], v = qf[2 * j + 1];
      pA[j] = fmaf(aA.x, u.x, fmaf(aA.y, u.y, fmaf(aA.z, u.z, fmaf(aA.w, u.w,
              fmaf(dA.x, v.x, fmaf(dA.y, v.y, fmaf(dA.z, v.z, dA.w * v.w)))))));
      pB[j] = fmaf(aB.x, u.x, fmaf(aB.y, u.y, fmaf(aB.z, u.z, fmaf(aB.w, u.w,
              fmaf(dB.x, v.x, fmaf(dB.y, v.y, fmaf(dB.z, v.z, dB.w * v.w)))))));
    }
    DPPADD(pA[0], pA[1], 0xB1);  DPPADD(pB[0], pB[1], 0xB1);
    DPPADD(pA[2], pA[3], 0xB1);  DPPADD(pB[2], pB[3], 0xB1);
    DPPADD(pA[4], pA[5], 0xB1);  DPPADD(pB[4], pB[5], 0xB1);
    DPPADD(pA[6], pA[7], 0xB1);  DPPADD(pB[6], pB[7], 0xB1);
    DPPADD(pA[0], pA[2], 0x4E);  DPPADD(pB[0], pB[2], 0x4E);
    DPPADD(pA[4], pA[6], 0x4E);  DPPADD(pB[4], pB[6], 0x4E);
    DPPADD(pA[0], pA[4], 0x141); DPPADD(pB[0], pB[4], 0x141);
    DPPADD(pA[0], pA[0], 0x128); DPPADD(pB[0], pB[0], 0x128);
    pA[0] += __shfl_xor(pA[0], 16, 64);
    pB[0] += __shfl_xor(pB[0], 16, 64);
    pA[0] += __shfl_xor(pA[0], 32, 64);
    pB[0] += __shfl_xor(pB[0], 32, 64);
    float eA = __expf(pA[0] * 0.125f);
    float eB = __expf(pB[0] * 0.125f);
    lp += eA + eB;
    float wA[8], wB[8];
#pragma unroll
    for (int h = 0; h < HH; ++h) {
      wA[h] = __uint_as_float(__builtin_amdgcn_readlane(__float_as_uint(eA), h));
      wB[h] = __uint_as_float(__builtin_amdgcn_readlane(__float_as_uint(eB), h));
    }
#pragma unroll
    for (int h = 0; h < HH; ++h) {
      float w1 = wA[h], w2 = wB[h];
      acc[2 * h].x = fmaf(w1, aA.x, acc[2 * h].x);
      acc[2 * h].y = fmaf(w1, aA.y, acc[2 * h].y);
      acc[2 * h].z = fmaf(w1, aA.z, acc[2 * h].z);
      acc[2 * h].w = fmaf(w1, aA.w, acc[2 * h].w);
      acc[2 * h + 1].x = fmaf(w1, dA.x, acc[2 * h + 1].x);
      acc[2 * h + 1].y = fmaf(w1, dA.y, acc[2 * h + 1].y);
      acc[2 * h + 1].z = fmaf(w1, dA.z, acc[2 * h + 1].z);
      acc[2 * h + 1].w = fmaf(w1, dA.w, acc[2 * h + 1].w);
      acc[2 * h].x = fmaf(w2, aB.x, acc[2 * h].x);
      acc[2 * h].y = fmaf(w2, aB.y, acc[2 * h].y);
      acc[2 * h].z = fmaf(w2, aB.z, acc[2 * h].z);
      acc[2 * h].w = fmaf(w2, aB.w, acc[2 * h].w);
      acc[2 * h + 1].x = fmaf(w2, dB.x, acc[2 * h + 1].x);
      acc[2 * h + 1].y = fmaf(w2, dB.y, acc[2 * h + 1].y);
      acc[2 * h + 1].z = fmaf(w2, dB.z, acc[2 * h + 1].z);
      acc[2 * h + 1].w = fmaf(w2, dB.w, acc[2 * h + 1].w);
    }
  }

  if (lane < 8) lbuf[wave * 8 + lane] = lp;

  for (int i = tid; i < HH * EE; i += 256) cbuf[i] = 0.f;
  __syncthreads();
  for (int w4 = 0; w4 < 4; ++w4) {
    if (wave == w4) {
#pragma unroll
      for (int h = 0; h < HH; ++h) {
        int e0 = h * EE + 4 * lane;
        cbuf[e0 + 0] += acc[2 * h].x;
        cbuf[e0 + 1] += acc[2 * h].y;
        cbuf[e0 + 2] += acc[2 * h].z;
        cbuf[e0 + 3] += acc[2 * h].w;
        int e1 = e0 + 256;
        cbuf[e1 + 0] += acc[2 * h + 1].x;
        cbuf[e1 + 1] += acc[2 * h + 1].y;
        cbuf[e1 + 2] += acc[2 * h + 1].z;
        cbuf[e1 + 3] += acc[2 * h + 1].w;
      }
    }
    __syncthreads();
  }
  float* pb = part + (size_t)b * (HH * EE);
  for (int i = tid; i < HH * EE; i += 256) pb[i] = cbuf[i];
  if (tid < 8)
    lw[b * 8 + tid] = lbuf[tid] + lbuf[8 + tid] + lbuf[16 + tid] + lbuf[24 + tid];
}

// ---- K3: ctx[n*8+h][e] = (sum_c part) / (sum_c lw)  ------------------------
__global__ __launch_bounds__(256) void k_combine(const float* __restrict__ part,
                                                 const float* __restrict__ lw,
                                                 float* __restrict__ ctx) {
  int t = blockIdx.x * 256 + threadIdx.x;  // 131072
  int n = t >> 12, x = t & 4095, h = x >> 9;
  float s = 0.f, lt = 0.f;
#pragma unroll
  for (int c = 0; c < NCHUNK; ++c) {
    s += part[(size_t)(n * NCHUNK + c) * 4096 + x];
    lt += lw[(n * NCHUNK + c) * 8 + h];
  }
  ctx[t] = s / lt;
}

// ---- K4-K6: wide GEMV. y[n,r] = x[row(n,r), :] . W[r,:] + b[r].
// Grid 2048 = (r, n-octet g); 1 wave. W row coalesced (64 lanes x float4 x 2).
// 8 outputs per wave via DPP slot-fold (masks 1,2,7 + xor8/16/32).
// HMAP=1: x rows are ctx[n*8+h] with h = r>>6 (Wv stage); else x rows = n.
template <int HMAP>
__global__ __launch_bounds__(64) void k_gemv(const float* __restrict__ x,
                                             const float* __restrict__ W,
                                             const float* __restrict__ bias,
                                             float* __restrict__ y) {
  int r = blockIdx.x >> 2, g = blockIdx.x & 3;
  int lane = threadIdx.x;
  const float4* W4 = (const float4*)W;
  const float4* x4 = (const float4*)x;
  float4 w0 = W4[r * 128 + lane];
  float4 w1 = W4[r * 128 + 64 + lane];
  const int SLOT[8] = {0, 1, 2, 3, 7, 6, 5, 4};
  float acc[8];
#pragma unroll
  for (int j = 0; j < 8; ++j) {
    int n = g * 8 + ((lane & 7) ^ SLOT[j]);
    int row = HMAP ? (n * 8 + (r >> 6)) : n;
    float4 a = x4[row * 128 + lane], d = x4[row * 128 + 64 + lane];
    acc[j] = fmaf(a.x, w0.x, fmaf(a.y, w0.y, fmaf(a.z, w0.z, fmaf(a.w, w0.w,
             fmaf(d.x, w1.x, fmaf(d.y, w1.y, fmaf(d.z, w1.z, d.w * w1.w)))))));
  }
  DPPADD(acc[0], acc[1], 0xB1);
  DPPADD(acc[2], acc[3], 0xB1);
  DPPADD(acc[4], acc[5], 0xB1);
  DPPADD(acc[6], acc[7], 0xB1);
  DPPADD(acc[0], acc[2], 0x4E);
  DPPADD(acc[4], acc[6], 0x4E);
  DPPADD(acc[0], acc[4], 0x141);
  DPPADD(acc[0], acc[0], 0x128);
  acc[0] += __shfl_xor(acc[0], 16, 64);
  acc[0] += __shfl_xor(acc[0], 32, 64);
  if (lane < 8) y[(size_t)(g * 8 + lane) * EE + r] = acc[0] + bias[r];
}

extern "C" void kernel_launch(void* const* d_in, const int* in_sizes, int n_in,
                              void* d_out, int out_size, void* d_ws, size_t ws_size,
                              hipStream_t stream) {
  const float* src = (const float*)d_in[0];
  const float* Wq  = (const float*)d_in[1];
  const float* bq  = (const float*)d_in[2];
  const float* Wk  = (const float*)d_in[3];
  const float* Wv  = (const float*)d_in[5];
  const float* bv  = (const float*)d_in[6];
  const float* Wo  = (const float*)d_in[7];
  const float* bo  = (const float*)d_in[8];
  const float* Wl  = (const float*)d_in[9];
  const float* bl  = (const float*)d_in[10];
  float* out = (float*)d_out;

  float* ws = (float*)d_ws;
  float* qk   = ws;                               // 131072
  float* lw   = qk + 131072;                      // 512*8 = 4096
  float* ctx  = lw + 4096;                        // 131072
  float* vout = ctx + 131072;                     // 16384
  float* y1   = vout + 16384;                     // 16384
  float* part = y1 + 16384;                       // 512*4096 floats (8MB)

  k_qproj<<<256, 256, 0, stream>>>(src, Wq, bq, Wk, qk);
  k_fused<<<NB * NCHUNK, 256, 0, stream>>>(src, qk, part, lw);
  k_combine<<<512, 256, 0, stream>>>(part, lw, ctx);
  k_gemv<1><<<2048, 64, 0, stream>>>(ctx, Wv, bv, vout);
  k_gemv<0><<<2048, 64, 0, stream>>>(vout, Wo, bo, y1);
  k_gemv<0><<<2048, 64, 0, stream>>>(y1, Wl, bl, out);
}